// Round 3
// baseline (436.712 us; speedup 1.0000x reference)
//
#include <hip/hip_runtime.h>

#define L_SEQ 100
#define E_DIM 100
#define G_DIM 192   // 3*H
#define B_TOT 4096
#define ROWS  4     // batch rows per recurrent block (1 wave per row)
#define SP    194   // fp32 scratch stride (2-way banks = free)
#define HBP   72    // h_bf stride in bf16

typedef __attribute__((ext_vector_type(8))) short bf16x8;
typedef __attribute__((ext_vector_type(4))) float f32x4;
typedef __attribute__((ext_vector_type(4))) float float4v;
typedef __attribute__((ext_vector_type(2))) float float2v;

static __device__ __forceinline__ unsigned short f2bf(float f) {
    union { float f; unsigned u; } v; v.f = f;
    unsigned r = v.u + 0x7FFFu + ((v.u >> 16) & 1u);  // RNE
    return (unsigned short)(r >> 16);
}
static __device__ __forceinline__ float bf2f(unsigned short u) {
    union { unsigned u; float f; } v; v.u = ((unsigned)u) << 16;
    return v.f;
}
static __device__ __forceinline__ float sigmoidf_(float x) { return 1.f / (1.f + __expf(-x)); }
static __device__ __forceinline__ float tanhf_(float x)    { return 1.f - 2.f / (__expf(2.f * x) + 1.f); }

// ---------------- pre-pass: tiw = bf16( x @ W_in + b_in ), optional per-row stats ----------------
// grid: (B*L)/16 blocks of 256 (4 waves, one 48-col n-slice each)
template<int STATS>
__global__ __launch_bounds__(256, 4) void ti_proj_kernel(
    const float* __restrict__ x, const float* __restrict__ Win,
    const float* __restrict__ bin, unsigned short* __restrict__ tiw,
    float* __restrict__ stats)
{
    __shared__ float xs[1600];               // 16 rows x 100 floats, staged coalesced
    __shared__ unsigned short T[16][200];    // 400 B rows (192 valid cols)
    __shared__ float Ps[4][16], Pss[4][16];

    const int tid = threadIdx.x;
    const int w   = tid >> 6, l = tid & 63;
    const int c16 = l & 15,  g = l >> 4;
    const int m0  = blockIdx.x * 16;
    const int colg = w * 48 + c16;

    // coalesced stage of the 16x100 x-slab (400 float4 chunks)
    {
        const float* xsrc = x + (size_t)m0 * E_DIM;
        *(float4v*)&xs[4 * tid] = *(const float4v*)&xsrc[4 * tid];
        if (tid < 144) {
            int j = tid + 256;
            *(float4v*)&xs[4 * j] = *(const float4v*)&xsrc[4 * j];
        }
    }

    // B frags: Win[32kt+8g+j][colg+16nt], zero-padded past k=100 (issued during stage)
    bf16x8 bw[4][3];
    #pragma unroll
    for (int kt = 0; kt < 4; ++kt)
      #pragma unroll
      for (int nt = 0; nt < 3; ++nt)
        #pragma unroll
        for (int j = 0; j < 8; ++j) {
            int k = 32 * kt + 8 * g + j;
            float v = (k < E_DIM) ? Win[k * G_DIM + colg + 16 * nt] : 0.f;
            bw[kt][nt][j] = (short)f2bf(v);
        }
    float bv[3];
    #pragma unroll
    for (int nt = 0; nt < 3; ++nt) bv[nt] = bin[colg + 16 * nt];

    __syncthreads();

    // A frags from xs row c16
    bf16x8 ax[4];
    #pragma unroll
    for (int kt = 0; kt < 4; ++kt) {
        int k0 = 32 * kt + 8 * g;
        float xv[8];
        if (k0 + 7 < E_DIM) {
            *(float4v*)&xv[0] = *(const float4v*)&xs[c16 * E_DIM + k0];
            *(float4v*)&xv[4] = *(const float4v*)&xs[c16 * E_DIM + k0 + 4];
        } else {
            #pragma unroll
            for (int j = 0; j < 8; ++j) {
                int k = k0 + j;
                xv[j] = (k < E_DIM) ? xs[c16 * E_DIM + k] : 0.f;
            }
        }
        #pragma unroll
        for (int j = 0; j < 8; ++j) ax[kt][j] = (short)f2bf(xv[j]);
    }

    const f32x4 zero = {0.f, 0.f, 0.f, 0.f};
    f32x4 acc[3] = {zero, zero, zero};
    #pragma unroll
    for (int nt = 0; nt < 3; ++nt)
      #pragma unroll
      for (int kt = 0; kt < 4; ++kt)
        acc[nt] = __builtin_amdgcn_mfma_f32_16x16x32_bf16(ax[kt], bw[kt][nt], acc[nt], 0, 0, 0);
    #pragma unroll
    for (int nt = 0; nt < 3; ++nt)
      #pragma unroll
      for (int rr = 0; rr < 4; ++rr) acc[nt][rr] += bv[nt];

    if constexpr (STATS) {
        // per-row (48-col partial) sums within wave, then 16-lane reduce
        float s[4], ss[4];
        #pragma unroll
        for (int rr = 0; rr < 4; ++rr) {
            s[rr]  = acc[0][rr] + acc[1][rr] + acc[2][rr];
            ss[rr] = acc[0][rr] * acc[0][rr] + acc[1][rr] * acc[1][rr] + acc[2][rr] * acc[2][rr];
        }
        #pragma unroll
        for (int m = 1; m < 16; m <<= 1)
          #pragma unroll
          for (int rr = 0; rr < 4; ++rr) {
              s[rr]  += __shfl_xor(s[rr], m);
              ss[rr] += __shfl_xor(ss[rr], m);
          }
        if (c16 == 0)
          #pragma unroll
          for (int rr = 0; rr < 4; ++rr) {
              Ps[w][4 * g + rr]  = s[rr];
              Pss[w][4 * g + rr] = ss[rr];
          }
    }

    #pragma unroll
    for (int nt = 0; nt < 3; ++nt)
      #pragma unroll
      for (int rr = 0; rr < 4; ++rr)
        T[4 * g + rr][colg + 16 * nt] = f2bf(acc[nt][rr]);
    __syncthreads();

    if constexpr (STATS) {
        if (tid < 16) {
            float s  = Ps[0][tid] + Ps[1][tid] + Ps[2][tid] + Ps[3][tid];
            float q2 = Pss[0][tid] + Pss[1][tid] + Pss[2][tid] + Pss[3][tid];
            float m  = s * (1.f / G_DIM);
            float var = (q2 - (float)G_DIM * m * m) * (1.f / (G_DIM - 1));
            stats[2 * (m0 + tid)]     = m;
            stats[2 * (m0 + tid) + 1] = rsqrtf(fmaxf(var, 1e-24f));
        }
    }

    // coalesced 16B stores: 384 chunks (16 rows x 24)
    {
        int row = tid / 24, j = tid - row * 24;
        *(float4v*)(tiw + (size_t)(m0 + row) * G_DIM + j * 8) =
            *(const float4v*)((const char*)&T[0][0] + row * 400 + j * 16);
        if (tid < 128) {
            int c2 = tid + 256, row2 = c2 / 24, j2 = c2 - row2 * 24;
            *(float4v*)(tiw + (size_t)(m0 + row2) * G_DIM + j2 * 8) =
                *(const float4v*)((const char*)&T[0][0] + row2 * 400 + j2 * 16);
        }
    }
}

// ---------------- recurrent kernel ----------------
// MODE 0: tiw + precomputed stats.  MODE 2: tiw, in-kernel ti stats.  MODE 1: inline from x.
template<int MODE>
__global__ __launch_bounds__(256, 4) void gru_rec_kernel(
    const float* __restrict__ x, const unsigned short* __restrict__ tiw,
    const float* __restrict__ stats,
    const float* __restrict__ Win, const float* __restrict__ bin,
    const float* __restrict__ Wh,  const float* __restrict__ bh,
    const float* __restrict__ Wfc, const float* __restrict__ bfc,
    float* __restrict__ out)
{
    __shared__ float S_th[16][SP];
    __shared__ float S_ti[(MODE == 1) ? 16 : 1][SP];
    __shared__ unsigned short h_bf[16][HBP];
    __shared__ float bh_l[G_DIM];
    __shared__ float bin_l[(MODE == 1) ? G_DIM : 1];

    const int tid = threadIdx.x;
    const int w   = tid >> 6, l = tid & 63;
    const int c16 = l & 15,  g = l >> 4;
    const int colg = w * 48 + c16;
    const int row0 = blockIdx.x * ROWS;
    const int row  = w;            // gate row == wave index
    const int q    = l;            // gate col in [0,64)

    if (tid < G_DIM) {
        bh_l[tid] = bh[tid];
        if constexpr (MODE == 1) bin_l[tid] = bin[tid];
    }
    for (int i = tid; i < 16 * HBP; i += 256) (&h_bf[0][0])[i] = 0;

    // W_h fragments (K=64)
    bf16x8 bwh[2][3];
    #pragma unroll
    for (int kt = 0; kt < 2; ++kt)
      #pragma unroll
      for (int nt = 0; nt < 3; ++nt)
        #pragma unroll
        for (int j = 0; j < 8; ++j) {
            int k = 32 * kt + 8 * g + j;
            bwh[kt][nt][j] = (short)f2bf(Wh[k * G_DIM + colg + 16 * nt]);
        }

    bf16x8 bwin[4][3];
    const float* xlane = nullptr;
    if constexpr (MODE == 1) {
        #pragma unroll
        for (int kt = 0; kt < 4; ++kt)
          #pragma unroll
          for (int nt = 0; nt < 3; ++nt)
            #pragma unroll
            for (int j = 0; j < 8; ++j) {
                int k = 32 * kt + 8 * g + j;
                float v = (k < E_DIM) ? Win[k * G_DIM + colg + 16 * nt] : 0.f;
                bwin[kt][nt][j] = (short)f2bf(v);
            }
        int xr = row0 + c16;
        if (xr > B_TOT - 1) xr = B_TOT - 1;
        xlane = x + (size_t)xr * (L_SEQ * E_DIM);
    }

    const unsigned short* tibase = (MODE != 1)
        ? tiw + (size_t)(row0 + row) * L_SEQ * G_DIM + q : nullptr;
    const float* statsbase = (MODE == 0)
        ? stats + 2 * (size_t)(row0 + row) * L_SEQ : nullptr;

    float hq = 0.f;   // fp32 master h for (row, col q)
    __syncthreads();

    for (int s = 0; s < 2 * L_SEQ; ++s) {
        const int t = (s < L_SEQ) ? s : s - L_SEQ;
        const bool phase = (s >= L_SEQ);

        // ---------- GEMM phase ----------
        unsigned short tiC[3];
        if constexpr (MODE != 1) {
            const unsigned short* tp = tibase + (size_t)t * G_DIM;
            #pragma unroll
            for (int i = 0; i < 3; ++i) tiC[i] = tp[64 * i];
        }
        float st_m = 0.f, st_r = 1.f;
        if constexpr (MODE == 0) {
            if (phase) {
                float2v sv = *(const float2v*)(statsbase + 2 * t);
                st_m = sv[0]; st_r = sv[1];
            }
        }

        bf16x8 ah0 = *(const bf16x8*)&h_bf[c16][8 * g];
        bf16x8 ah1 = *(const bf16x8*)&h_bf[c16][32 + 8 * g];

        const f32x4 zero = {0.f, 0.f, 0.f, 0.f};
        f32x4 acch[3];
        #pragma unroll
        for (int nt = 0; nt < 3; ++nt) {
            acch[nt] = __builtin_amdgcn_mfma_f32_16x16x32_bf16(ah0, bwh[0][nt], zero,     0, 0, 0);
            acch[nt] = __builtin_amdgcn_mfma_f32_16x16x32_bf16(ah1, bwh[1][nt], acch[nt], 0, 0, 0);
        }
        f32x4 acci[3];
        if constexpr (MODE == 1) {
            bf16x8 axx[4];
            const float* xp = xlane + t * E_DIM;
            #pragma unroll
            for (int kt = 0; kt < 4; ++kt) {
                int k0 = 32 * kt + 8 * g;
                float xv[8];
                if (k0 + 7 < E_DIM) {
                    *(float4v*)&xv[0] = *(const float4v*)&xp[k0];
                    *(float4v*)&xv[4] = *(const float4v*)&xp[k0 + 4];
                } else {
                    #pragma unroll
                    for (int j = 0; j < 8; ++j) { int k = k0 + j; xv[j] = (k < E_DIM) ? xp[k] : 0.f; }
                }
                #pragma unroll
                for (int j = 0; j < 8; ++j) axx[kt][j] = (short)f2bf(xv[j]);
            }
            #pragma unroll
            for (int nt = 0; nt < 3; ++nt) {
                acci[nt] = zero;
                #pragma unroll
                for (int kt = 0; kt < 4; ++kt)
                    acci[nt] = __builtin_amdgcn_mfma_f32_16x16x32_bf16(axx[kt], bwin[kt][nt], acci[nt], 0, 0, 0);
            }
        }
        #pragma unroll
        for (int nt = 0; nt < 3; ++nt)
          #pragma unroll
          for (int rr = 0; rr < 4; ++rr) {
              S_th[4 * g + rr][colg + 16 * nt] = acch[nt][rr];
              if constexpr (MODE == 1) S_ti[4 * g + rr][colg + 16 * nt] = acci[nt][rr];
          }
        __syncthreads();

        // ---------- gate phase: one (r,z,n) triple per thread ----------
        float a[3], b[3];
        #pragma unroll
        for (int i = 0; i < 3; ++i) {
            int c = q + 64 * i;
            if constexpr (MODE == 1) a[i] = S_ti[row][c] + bin_l[c];
            else                     a[i] = bf2f(tiC[i]);
            b[i] = S_th[row][c] + bh_l[c];
        }
        float mti = 0.f, rti = 1.f, mth = 0.f, rth = 1.f;
        if (phase) {
            float sth  = b[0] + b[1] + b[2];
            float ssth = b[0] * b[0] + b[1] * b[1] + b[2] * b[2];
            float sti = 0.f, ssti = 0.f;
            if constexpr (MODE != 0) {
                sti  = a[0] + a[1] + a[2];
                ssti = a[0] * a[0] + a[1] * a[1] + a[2] * a[2];
            }
            #pragma unroll
            for (int m = 1; m < 64; m <<= 1) {
                sth += __shfl_xor(sth, m); ssth += __shfl_xor(ssth, m);
                if constexpr (MODE != 0) { sti += __shfl_xor(sti, m); ssti += __shfl_xor(ssti, m); }
            }
            mth = sth * (1.f / G_DIM);
            rth = rsqrtf(fmaxf((ssth - (float)G_DIM * mth * mth) * (1.f / (G_DIM - 1)), 1e-24f));
            if constexpr (MODE == 0) { mti = st_m; rti = st_r; }
            else {
                mti = sti * (1.f / G_DIM);
                rti = rsqrtf(fmaxf((ssti - (float)G_DIM * mti * mti) * (1.f / (G_DIM - 1)), 1e-24f));
            }
        }
        float tir, tiz, tin, thr2, thz, thn;
        if (phase) {
            tir  = (a[0] - mti) * rti; tiz = (a[1] - mti) * rti; tin = (a[2] - mti) * rti;
            thr2 = (b[0] - mth) * rth; thz = (b[1] - mth) * rth; thn = (b[2] - mth) * rth;
        } else {
            tir = a[0]; tiz = a[1]; tin = a[2];
            thr2 = b[0]; thz = b[1]; thn = b[2];
        }
        float rt  = sigmoidf_(tir + thr2);
        float zt  = sigmoidf_(tiz + thz);
        float nv  = tanhf_(tin + rt * thn);
        hq = (1.f - zt) * nv + zt * hq;
        h_bf[row][q] = f2bf(hq);
        __syncthreads();
    }

    // ---------- epilogue: out = h @ W_fc + b_fc ----------
    float p0 = hq * Wfc[2 * q];
    float p1 = hq * Wfc[2 * q + 1];
    #pragma unroll
    for (int m = 1; m < 64; m <<= 1) {
        p0 += __shfl_xor(p0, m);
        p1 += __shfl_xor(p1, m);
    }
    if (q == 0) {
        out[(row0 + row) * 2 + 0] = p0 + bfc[0];
        out[(row0 + row) * 2 + 1] = p1 + bfc[1];
    }
}

extern "C" void kernel_launch(void* const* d_in, const int* in_sizes, int n_in,
                              void* d_out, int out_size, void* d_ws, size_t ws_size,
                              hipStream_t stream) {
    const float* x   = (const float*)d_in[0];
    const float* Win = (const float*)d_in[1];
    const float* bin = (const float*)d_in[2];
    const float* Wh  = (const float*)d_in[3];
    const float* bh  = (const float*)d_in[4];
    const float* Wfc = (const float*)d_in[5];
    const float* bfc = (const float*)d_in[6];
    float* out = (float*)d_out;

    const size_t stats_b = (size_t)B_TOT * L_SEQ * 2 * sizeof(float);              // 3.28 MB
    const size_t tiw_b   = (size_t)B_TOT * L_SEQ * G_DIM * sizeof(unsigned short); // 157.3 MB
    const int pre_grid = B_TOT * L_SEQ / 16;
    const int rec_grid = B_TOT / ROWS;

    if (ws_size >= stats_b + tiw_b) {
        float* stats = (float*)d_ws;
        unsigned short* tiw = (unsigned short*)((char*)d_ws + stats_b);
        ti_proj_kernel<1><<<dim3(pre_grid), dim3(256), 0, stream>>>(x, Win, bin, tiw, stats);
        gru_rec_kernel<0><<<dim3(rec_grid), dim3(256), 0, stream>>>(
            x, tiw, stats, Win, bin, Wh, bh, Wfc, bfc, out);
    } else if (ws_size >= tiw_b) {
        unsigned short* tiw = (unsigned short*)d_ws;
        ti_proj_kernel<0><<<dim3(pre_grid), dim3(256), 0, stream>>>(x, Win, bin, tiw, nullptr);
        gru_rec_kernel<2><<<dim3(rec_grid), dim3(256), 0, stream>>>(
            x, tiw, nullptr, Win, bin, Wh, bh, Wfc, bfc, out);
    } else {
        gru_rec_kernel<1><<<dim3(rec_grid), dim3(256), 0, stream>>>(
            x, nullptr, nullptr, Win, bin, Wh, bh, Wfc, bfc, out);
    }
}